// Round 7
// baseline (136.215 us; speedup 1.0000x reference)
//
#include <hip/hip_runtime.h>
#include <stdint.h>
#include <stddef.h>

// Problem: out[b,a,o] = sum_{i,j} h0[b,a,i] h1[b,a,j] T[a,i,j,o], h=concat(x,1)
// GEMM form: C[b,o] += G[b,k]*Tb[a,k,o]; main k=j*128+i (i,j<128); k=16384+c:
// G=h1[c]; k=16512+c: G=h0[c]; k=16640: G=1. 261 K-tiles of 64.
#define NA     4
#define DDIM   128
#define OUTD   128
#define BM     128
#define BN     128
#define NTILES 261
#define TILE_B 16384          // BN * 64 * 2B
#define OUT_ELEMS (4096 * NA * OUTD)   // 2,097,152 f32

typedef _Float16 f16;
typedef __attribute__((ext_vector_type(8)))  _Float16 f16x8;
typedef __attribute__((ext_vector_type(4)))  float    f32x4;
typedef __attribute__((ext_vector_type(16))) float    f32x16;

static const size_t TB_BYTES  = (size_t)NA * NTILES * TILE_B;          // 17,104,896
static const size_t P_BYTES   = (size_t)4 * OUT_ELEMS * sizeof(float); // 33,554,432
static const size_t WS_NEEDED = TB_BYTES + P_BYTES;                    // ~50.7 MB

// ---------------------------------------------------------------------------
// Prep: T f32 -> Tb f16, per (a,tile) a 16KB image; unit v = w*128+col
// (w=0..7) holds k = tile*64 + w*8 + e at output-col `col`.
// ---------------------------------------------------------------------------
__global__ __launch_bounds__(256) void prep_kernel(const float* __restrict__ T,
                                                   f16* __restrict__ Tb) {
    int blk  = blockIdx.x;            // a*NTILES + tile
    int a    = blk / NTILES;
    int tile = blk - a * NTILES;
    int t    = threadIdx.x;
    f16* base = Tb + (size_t)blk * (TILE_B / 2);
    #pragma unroll
    for (int u = 0; u < 4; ++u) {
        int v   = t + u * 256;
        int w   = v >> 7;
        int col = v & 127;
        f16x8 ov;
        #pragma unroll
        for (int e = 0; e < 8; ++e) {
            int k = tile * 64 + w * 8 + e;
            int i = -1, j = 0;
            if (k < 16384)       { i = k & 127;   j = k >> 7;    }
            else if (k < 16512)  { i = 128;       j = k - 16384; }
            else if (k < 16640)  { i = k - 16512; j = 128;       }
            else if (k == 16640) { i = 128;       j = 128;       }
            float val = 0.f;
            if (i >= 0) val = T[(((size_t)a * 129 + i) * 129 + j) * 128 + col];
            ov[e] = (f16)val;
        }
        *(f16x8*)(base + (size_t)v * 8) = ov;
    }
}

__device__ __forceinline__ f16x8 pack_f16x8(f32x4 a, f32x4 b) {
    f16x8 h;
    #pragma unroll
    for (int e = 0; e < 4; ++e) { h[e] = (f16)a[e]; h[e + 4] = (f16)b[e]; }
    return h;
}

// ---------------------------------------------------------------------------
// GEMM: BM=128 x BN=128, 16 waves (4M x 4N), wave = 32 rows x 32 cols (fm=1).
// EVERYTHING register-resident: h0 (8 windows, 32 VGPR), h1 j-window (16),
// acc (16), B double-buffer (32). Zero LDS, zero barriers, zero ds_read.
// 1024-thr block -> 1 block/CU, 4 waves/SIMD (grid 512 = 2 serial passes).
// B fragments direct global->reg (prep layout == fragment layout).
// ---------------------------------------------------------------------------
template <bool ATOMIC>
__global__ __launch_bounds__(1024, 4) void gemm_kernel(const float* __restrict__ x0,
                                                       const float* __restrict__ x1,
                                                       const f16* __restrict__ Tb,
                                                       float* __restrict__ dst) {
    int bid  = blockIdx.x;
    int xcd  = bid & 7, idx = bid >> 3;      // idx in [0,64)
    int pair = xcd * 2 + (idx >> 5);         // 2 (a,ks) pairs per XCD
    int mt   = idx & 31;
    int a    = pair & 3;
    int ks   = pair >> 2;

    int t    = threadIdx.x;
    int lane = t & 63, wid = t >> 6;         // 16 waves
    int wm   = wid >> 2, wn = wid & 3;       // 4M x 4N
    int l31  = lane & 31, hi = lane >> 5;
    int b0   = mt * BM;
    int row  = b0 + wm * 32 + l31;           // this lane's M row

    const char* tbb = (const char*)Tb + (size_t)a * NTILES * TILE_B;
    int nt = (ks == 1) ? 66 : 65;

    // per-lane B pointer (fragment layout == prep global layout)
    const char* bp = tbb + (size_t)(ks * 64) * TILE_B + hi * 2048 + (wn * 32 + l31) * 16;

    f16x8 bA[4], bB[4];
    #pragma unroll
    for (int kk = 0; kk < 4; ++kk) bA[kk] = *(const f16x8*)(bp + kk * 4096);
    #pragma unroll
    for (int kk = 0; kk < 4; ++kk) bB[kk] = *(const f16x8*)(bp + TILE_B + kk * 4096);

    // ---- h0 -> registers: 8 windows (wf = 2w + hi) of this lane's row ----
    const float* x0r = x0 + ((size_t)row * NA + a) * DDIM;
    f16x8 h0reg[8];
    #pragma unroll
    for (int w = 0; w < 8; ++w) {
        int wf = 2 * w + hi;
        h0reg[w] = pack_f16x8(*(const f32x4*)(x0r + wf * 8),
                              *(const f32x4*)(x0r + wf * 8 + 4));
    }
    // ---- h1 j-window -> registers: 32 j's starting at ks*32 ----
    const float* x1r = x1 + ((size_t)row * NA + a) * DDIM;
    f16x8 h1r0 = pack_f16x8(*(const f32x4*)(x1r + ks * 32 +  0), *(const f32x4*)(x1r + ks * 32 +  4));
    f16x8 h1r1 = pack_f16x8(*(const f32x4*)(x1r + ks * 32 +  8), *(const f32x4*)(x1r + ks * 32 + 12));
    f16x8 h1r2 = pack_f16x8(*(const f32x4*)(x1r + ks * 32 + 16), *(const f32x4*)(x1r + ks * 32 + 20));
    f16x8 h1r3 = pack_f16x8(*(const f32x4*)(x1r + ks * 32 + 24), *(const f32x4*)(x1r + ks * 32 + 28));

    f32x16 acc = (f32x16)0.f;

    // ---- main loop: 64 tiles as 4 groups of 8 j's; all indices static ----
    auto p8body = [&](f16x8 hv, int pbase) {
        #pragma unroll
        for (int pe = 0; pe < 8; ++pe) {
            f16 s = hv[pe];
            int tt0 = (pbase + pe) * 2;
            // tile tt0 (i-half 0): windows h0reg[kk]
            #pragma unroll
            for (int kk = 0; kk < 4; ++kk) {
                f16x8 af = h0reg[kk] * s;
                acc = __builtin_amdgcn_mfma_f32_32x32x16_f16(af, bA[kk], acc, 0, 0, 0);
            }
            {   int nxt = tt0 + 2; if (nxt > 63) nxt = 63;
                const char* q = bp + (size_t)nxt * TILE_B;
                #pragma unroll
                for (int kk = 0; kk < 4; ++kk) bA[kk] = *(const f16x8*)(q + kk * 4096);
            }
            // tile tt0+1 (i-half 1): windows h0reg[4+kk]
            #pragma unroll
            for (int kk = 0; kk < 4; ++kk) {
                f16x8 af = h0reg[4 + kk] * s;
                acc = __builtin_amdgcn_mfma_f32_32x32x16_f16(af, bB[kk], acc, 0, 0, 0);
            }
            {   int nxt = tt0 + 3; if (nxt > 63) nxt = 63;
                const char* q = bp + (size_t)nxt * TILE_B;
                #pragma unroll
                for (int kk = 0; kk < 4; ++kk) bB[kk] = *(const f16x8*)(q + kk * 4096);
            }
        }
    };
    p8body(h1r0, 0);
    p8body(h1r1, 8);
    p8body(h1r2, 16);
    p8body(h1r3, 24);

    // ---- correction tail (1-2 tiles, per-ks role) ----
    for (int tt = 64; tt < nt; ++tt) {
        int tile;
        if      (ks == 0) tile = 256;
        else if (ks == 1) tile = (tt == 64) ? 258 : 260;
        else if (ks == 2) tile = 257;
        else              tile = 259;
        const char* q = tbb + (size_t)tile * TILE_B + hi * 2048 + (wn * 32 + l31) * 16;
        f16x8 bt[4];
        #pragma unroll
        for (int kk = 0; kk < 4; ++kk) bt[kk] = *(const f16x8*)(q + kk * 4096);

        #pragma unroll
        for (int kk = 0; kk < 4; ++kk) {
            f16x8 af;
            if (ks == 0 || ks == 2) {            // j-corr: G = h1[c]
                int cb = (ks == 2) ? 64 : 0;
                af = pack_f16x8(*(const f32x4*)(x1r + cb + kk * 16 + hi * 8),
                                *(const f32x4*)(x1r + cb + kk * 16 + hi * 8 + 4));
            } else if (ks == 3) {                // i-corr hi: G = h0[64+c]
                af = h0reg[4 + kk];
            } else if (tt == 64) {               // ks==1: i-corr lo: G = h0[c]
                af = h0reg[kk];
            } else {                             // const tile: G = 1 at k_local 0
                af = (f16x8)(f16)0.f;
                if (kk == 0 && hi == 0) af[0] = (f16)1.f;
            }
            acc = __builtin_amdgcn_mfma_f32_32x32x16_f16(af, bt[kk], acc, 0, 0, 0);
        }
    }

    // ---- epilogue: C/D 32x32 layout col=lane&31, row=(r&3)+8*(r>>2)+4*hi ----
    float* base = ATOMIC ? dst : dst + (size_t)ks * OUT_ELEMS;
    #pragma unroll
    for (int r = 0; r < 16; ++r) {
        int orow = b0 + wm * 32 + (r & 3) + 8 * (r >> 2) + 4 * hi;
        int ocol = wn * 32 + l31;
        size_t off = ((size_t)orow * NA + a) * OUTD + ocol;
        if (ATOMIC) unsafeAtomicAdd(&base[off], acc[r]);
        else        base[off] = acc[r];
    }
}

// ---------------------------------------------------------------------------
// Reduce: out = P0 + P1 + P2 + P3 (f32x4 vectorized)
// ---------------------------------------------------------------------------
__global__ __launch_bounds__(256) void reduce_kernel(const float* __restrict__ P,
                                                     float* __restrict__ out) {
    int i = blockIdx.x * 256 + threadIdx.x;     // 524288 vec4 elems
    f32x4 s = ((const f32x4*)P)[i];
    s += ((const f32x4*)(P + OUT_ELEMS))[i];
    s += ((const f32x4*)(P + 2 * (size_t)OUT_ELEMS))[i];
    s += ((const f32x4*)(P + 3 * (size_t)OUT_ELEMS))[i];
    ((f32x4*)out)[i] = s;
}

// ---------------------------------------------------------------------------
// Fallback (ws too small): naive but correct f32 kernel.
// ---------------------------------------------------------------------------
__global__ __launch_bounds__(128) void fallback_kernel(const float* __restrict__ x0,
                                                       const float* __restrict__ x1,
                                                       const float* __restrict__ T,
                                                       float* __restrict__ out) {
    int ba = blockIdx.x;
    int b = ba >> 2, a = ba & 3;
    int o = threadIdx.x;
    const float* h0 = x0 + ((size_t)b * NA + a) * DDIM;
    const float* h1 = x1 + ((size_t)b * NA + a) * DDIM;
    float acc = 0.f;
    for (int i = 0; i < 129; ++i) {
        float h0i = (i < 128) ? h0[i] : 1.f;
        const float* Trow = T + (((size_t)a * 129 + i) * 129) * 128 + o;
        float part = 0.f;
        for (int j = 0; j < 129; ++j) {
            float h1j = (j < 128) ? h1[j] : 1.f;
            part += h1j * Trow[(size_t)j * 128];
        }
        acc += h0i * part;
    }
    out[((size_t)b * NA + a) * OUTD + o] = acc;
}

extern "C" void kernel_launch(void* const* d_in, const int* in_sizes, int n_in,
                              void* d_out, int out_size, void* d_ws, size_t ws_size,
                              hipStream_t stream) {
    const float* x0 = (const float*)d_in[0];
    const float* x1 = (const float*)d_in[1];
    const float* T  = (const float*)d_in[2];
    float* out = (float*)d_out;

    if (ws_size < TB_BYTES) {
        fallback_kernel<<<4096 * NA, 128, 0, stream>>>(x0, x1, T, out);
        return;
    }

    f16* Tb = (f16*)d_ws;
    prep_kernel<<<NA * NTILES, 256, 0, stream>>>(T, Tb);

    if (ws_size >= WS_NEEDED) {
        float* P = (float*)((char*)d_ws + TB_BYTES);
        gemm_kernel<false><<<512, 1024, 0, stream>>>(x0, x1, Tb, P);
        reduce_kernel<<<OUT_ELEMS / 4 / 256, 256, 0, stream>>>(P, out);
    } else {
        hipMemsetAsync(d_out, 0, (size_t)out_size * sizeof(float), stream);
        gemm_kernel<true><<<512, 1024, 0, stream>>>(x0, x1, Tb, out);
    }
}